// Round 2
// baseline (151.624 us; speedup 1.0000x reference)
//
#include <hip/hip_runtime.h>
#include <hip/hip_bf16.h>

// GraphConv (PyG, aggr='add') + ReLU on MI355X — fp32 in/out, bf16 internals.
//   out = relu( segment_sum(x[src] -> dst) @ W_rel^T + b_rel + x @ W_root^T )
// N=50000, E=800000, D=128.
//
// Round 12: main kernel was 65% stall (VALUBusy 35%, MfmaUtil 2.6%, occ 60%):
// per-node serial miss chain cnt->slots->rows, only 8 loads in flight.
// stage2 merged INTO the main kernel: block = half-bucket (32 dst nodes),
// reads its bucket's bmem records (coalesced) and builds cnt+slots in LDS.
// Deletes the stage2 dispatch, the slots global round-trip, and the
// dependency chain. Gather now processes node PAIRS (16 row loads in
// flight). Degree-overflow (>SLOTS) falls back to rescanning the bucket's
// records; bucket-overflow (>BCAP) still goes through the global ovf list.

#define N_NODES 50000
#define N_EDGES 800000
#define D 128
#define SLOTS 40    // LDS slots per node (deg ~Poisson(16); tail -> rescan)
#define NB 782      // buckets of 64 destination nodes (ceil(50000/64))
#define BCAP 1536   // records per bucket (expected 1024; tail -> ovf)
#define BINB 196    // bin blocks: 196 * 4096 edges >= 800000
#define NPB 32      // nodes per fp32-gemm block (mid tier)
#define KC 32       // k per chunk (mid tier)
#define SROW 136    // LDS agg-row stride (ushorts); 272 B rows, 2-way banks = free

#define CVT_N  (N_NODES * (D / 2))   // 3,200,000 ushort2 conversions
#define PACK_N (8 * 8 * 64 * 8)      // 32,768 packed B-fragment elements

typedef __attribute__((ext_vector_type(8))) short short8;   // 8 bf16 = 4 VGPRs
typedef __attribute__((ext_vector_type(4))) float floatx4;

__device__ __forceinline__ float bf2f(unsigned short u) {
    return __uint_as_float((unsigned int)u << 16);
}
__device__ __forceinline__ unsigned short f2bf(float f) {
    __hip_bfloat16 h = __float2bfloat16(f);
    return *(unsigned short*)&h;
}

// int64 node-id array => every odd int32 word is 0 (ids < 50000).
// Must run with all 64 lanes active (call before any early return).
__device__ __forceinline__ int wave_detect_i64(const int* __restrict__ ei) {
    int lane = threadIdx.x & 63;
    int v = ei[2 * lane + 1];
    return __ballot(v == 0) == ~0ull;
}

// ---------------- utility ----------------
__global__ __launch_bounds__(256) void zero_f4_kernel(float4* __restrict__ p, int n4) {
    int i = blockIdx.x * 256 + threadIdx.x;
    if (i < n4) p[i] = make_float4(0.f, 0.f, 0.f, 0.f);
}

// flag-based detect kept only for the low-tier scatter fallback
__global__ void detect_kernel(const int* __restrict__ ei, int* __restrict__ flag) {
    if (threadIdx.x == 0 && blockIdx.x == 0) {
        int any = 0;
        for (int i = 0; i < 64; ++i) any |= ei[2 * i + 1];
        flag[0] = (any == 0) ? 1 : 0;
    }
}

// ---------------- stage1: edge binning + cvt_x + pack_frag ----------------
// Blocks [0, BINB): bin 4096 edges each into NB buckets of 64 dst nodes.
// Blocks [BINB, ...): prep work (x -> bf16, W packing).
// gcur (NB ints) and ovf_cnt must be zeroed before launch (hipMemsetAsync).
__global__ __launch_bounds__(256) void stage1_kernel(const float2* __restrict__ x2,
                                                     ushort2* __restrict__ xb2,
                                                     const float* __restrict__ Wrel,
                                                     const float* __restrict__ Wroot,
                                                     unsigned short* __restrict__ pwc,
                                                     const int* __restrict__ ei,
                                                     int* __restrict__ gcur,
                                                     unsigned* __restrict__ bmem,
                                                     int* __restrict__ ovf_cnt,
                                                     int* __restrict__ ovf) {
    __shared__ int lds_cnt[NB];
    __shared__ int lds_base[NB];
    if (blockIdx.x < BINB) {
        int t = threadIdx.x;
        int i64 = wave_detect_i64(ei);
        for (int i = t; i < NB; i += 256) lds_cnt[i] = 0;
        __syncthreads();

        unsigned rec[16];
        int rnk[16];
#pragma unroll
        for (int g = 0; g < 4; ++g) {
            int base = blockIdx.x * 4096 + g * 1024 + t * 4;
            int s0 = -1, s1 = -1, s2 = -1, s3 = -1;
            int d0 = -1, d1 = -1, d2 = -1, d3 = -1;
            if (base < N_EDGES) {            // N_EDGES % 4 == 0: all-or-nothing
                if (i64) {
                    int4 a = *(const int4*)&ei[2 * base];
                    int4 b = *(const int4*)&ei[2 * base + 4];
                    s0 = a.x; s1 = a.z; s2 = b.x; s3 = b.z;
                    int4 c = *(const int4*)&ei[2 * N_EDGES + 2 * base];
                    int4 e = *(const int4*)&ei[2 * N_EDGES + 2 * base + 4];
                    d0 = c.x; d1 = c.z; d2 = e.x; d3 = e.z;
                } else {
                    int4 sv = *(const int4*)&ei[base];
                    int4 dv = *(const int4*)&ei[N_EDGES + base];
                    s0 = sv.x; s1 = sv.y; s2 = sv.z; s3 = sv.w;
                    d0 = dv.x; d1 = dv.y; d2 = dv.z; d3 = dv.w;
                }
            }
#define BINP(idx, ss, dd)                                                        \
            {                                                                    \
                bool ok = (unsigned)(ss) < N_NODES && (unsigned)(dd) < N_NODES;  \
                rec[idx] = ok ? (((unsigned)(dd) << 16) | (unsigned)(ss))        \
                              : 0xFFFFFFFFu;                                     \
                rnk[idx] = ok ? atomicAdd(&lds_cnt[(unsigned)(dd) >> 6], 1) : 0; \
            }
            BINP(g * 4 + 0, s0, d0)
            BINP(g * 4 + 1, s1, d1)
            BINP(g * 4 + 2, s2, d2)
            BINP(g * 4 + 3, s3, d3)
#undef BINP
        }
        __syncthreads();
        for (int i = t; i < NB; i += 256) {
            int c = lds_cnt[i];
            lds_base[i] = c ? atomicAdd(&gcur[i], c) : 0;
        }
        __syncthreads();
#pragma unroll
        for (int idx = 0; idx < 16; ++idx) {
            unsigned r = rec[idx];
            if (r != 0xFFFFFFFFu) {
                int bk = (int)(r >> 22);             // dst >> 6
                int pos = lds_base[bk] + rnk[idx];
                if (pos < BCAP) {
                    bmem[(size_t)bk * BCAP + pos] = r;
                } else {                             // bucket overflow: rare
                    int o = atomicAdd(ovf_cnt, 1);
                    ovf[2 * o] = (int)(r >> 16);
                    ovf[2 * o + 1] = (int)(r & 0xFFFFu);
                }
            }
        }
    } else {
        int i = (blockIdx.x - BINB) * 256 + threadIdx.x;
        if (i < CVT_N) {
            float2 f = x2[i];
            xb2[i] = make_ushort2(f2bf(f.x), f2bf(f.y));
        } else if (i < CVT_N + PACK_N) {
            // pwc[((t*8+n0)*64+lane)*8+j] = W_cat[n0*16+(lane&15)][t*32+(lane>>4)*8+j]
            int idx  = i - CVT_N;
            int j    = idx & 7;
            int lane = (idx >> 3) & 63;
            int n0   = (idx >> 9) & 7;
            int t    = idx >> 12;
            int n = n0 * 16 + (lane & 15);
            int k = t * 32 + (lane >> 4) * 8 + j;
            float w = (k < D) ? Wrel[n * D + k] : Wroot[n * D + (k - D)];
            pwc[idx] = f2bf(w);
        }
    }
}

// ---------------- fused stage2 + gather + MFMA GEMM + bias + ReLU ----------------
// Block = half-bucket = 32 dst nodes (grid 2*NB = 1564). Phase 1: stream this
// bucket's bmem records, build cnt+slots in LDS (filter by half). Phase 2:
// wave wid gathers 8 nodes as 4 PAIRS (16 row loads in flight; slot indices
// from LDS -> no global dependency chain). Phase 3: per-tile MFMA; wave wid
// computes n0 groups [ (wid&1)*4 .. +3 ] of tile (wid>>1).
// Degree overflow (kk > SLOTS): ignore slots, rescan bucket records (exact).
// Bucket overflow (> BCAP): handled via global ovf list (tov scan).
// Layouts (verified): A[m=lane&15][k=quad*8+j], D: col=lane&15, row=quad*4+reg.
__global__ __launch_bounds__(256) void GraphConvLayer_55783035240593_kernel(
        const ushort2* __restrict__ xb2,
        const unsigned short* __restrict__ xb,
        const int* __restrict__ gcur,
        const unsigned* __restrict__ bmem,
        const int* __restrict__ ovf_cnt,
        const int* __restrict__ ovf,
        const unsigned short* __restrict__ pwc,
        const float* __restrict__ b_rel,
        float* __restrict__ out) {
    __shared__ unsigned short sA[32 * SROW];        // 8704 B
    __shared__ unsigned short slotsL[32 * SLOTS];   // 2560 B
    __shared__ int lc[32];
    int t = threadIdx.x;
    int wid = t >> 6, lane = t & 63;
    int bkt = blockIdx.x >> 1, half = blockIdx.x & 1;
    int node0 = blockIdx.x * 32;

    if (t < 32) lc[t] = 0;
    __syncthreads();

    // ---- phase 1: build padded CSR in LDS from bucket records ----
    int n = gcur[bkt];
    if (n > BCAP) n = BCAP;                  // entries past BCAP went to ovf
    for (int e = t; e < n; e += 256) {
        unsigned r = bmem[(size_t)bkt * BCAP + e];
        int d = (int)(r >> 16);
        if (((d >> 5) & 1) != half) continue;
        int p = atomicAdd(&lc[d & 31], 1);
        if (p < SLOTS) slotsL[(d & 31) * SLOTS + p] = (unsigned short)(r & 0xFFFFu);
    }
    __syncthreads();
    int tov = ovf_cnt[0];                    // broadcast, L2-hot

    // ---- phase 2: gather, 8 nodes per wave, processed in pairs ----
    for (int pp = 0; pp < 4; ++pp) {
        int la = wid * 8 + pp * 2, lb = la + 1;
        int nodeA = node0 + la, nodeB = node0 + lb;
        int kkA = lc[la], kkB = lc[lb];
        int kA = (kkA > SLOTS) ? 0 : kkA;    // overflowed nodes: rescan path
        int kB = (kkB > SLOTS) ? 0 : kkB;
        int myA = (lane < kA) ? (int)slotsL[la * SLOTS + lane] : 0;
        int myB = (lane < kB) ? (int)slotsL[lb * SLOTS + lane] : 0;
        float axA = 0.f, ayA = 0.f, axB = 0.f, ayB = 0.f;
        int jmax = kA > kB ? kA : kB;
        for (int j = 0; j < jmax; j += 8) {
            bool doA = j < kA, doB = j < kB;
            ushort2 u[8], v[8];
            if (doA) {
                int s[8];
#pragma unroll
                for (int i = 0; i < 8; ++i) s[i] = __shfl(myA, j + i);
#pragma unroll
                for (int i = 0; i < 8; ++i) u[i] = xb2[(size_t)s[i] * (D / 2) + lane];
            }
            if (doB) {
                int s[8];
#pragma unroll
                for (int i = 0; i < 8; ++i) s[i] = __shfl(myB, j + i);
#pragma unroll
                for (int i = 0; i < 8; ++i) v[i] = xb2[(size_t)s[i] * (D / 2) + lane];
            }
            if (doA) {
#pragma unroll
                for (int i = 0; i < 8; ++i) {
                    float mm = (j + i < kA) ? 1.f : 0.f;
                    axA += mm * bf2f(u[i].x);
                    ayA += mm * bf2f(u[i].y);
                }
            }
            if (doB) {
#pragma unroll
                for (int i = 0; i < 8; ++i) {
                    float mm = (j + i < kB) ? 1.f : 0.f;
                    axB += mm * bf2f(v[i].x);
                    ayB += mm * bf2f(v[i].y);
                }
            }
        }
        if (kkA > SLOTS) {                   // rare: exact rescan of records
            for (int e = 0; e < n; ++e) {
                unsigned r = bmem[(size_t)bkt * BCAP + e];
                if ((int)(r >> 16) == nodeA) {
                    ushort2 uu = xb2[(size_t)(r & 0xFFFFu) * (D / 2) + lane];
                    axA += bf2f(uu.x); ayA += bf2f(uu.y);
                }
            }
        }
        if (kkB > SLOTS) {
            for (int e = 0; e < n; ++e) {
                unsigned r = bmem[(size_t)bkt * BCAP + e];
                if ((int)(r >> 16) == nodeB) {
                    ushort2 uu = xb2[(size_t)(r & 0xFFFFu) * (D / 2) + lane];
                    axB += bf2f(uu.x); ayB += bf2f(uu.y);
                }
            }
        }
        if (tov > 0) {                       // bucket-overflow entries: rare
            for (int e2 = 0; e2 < tov; ++e2) {
                int dd = ovf[2 * e2];
                if (dd == nodeA) {
                    ushort2 uu = xb2[(size_t)ovf[2 * e2 + 1] * (D / 2) + lane];
                    axA += bf2f(uu.x); ayA += bf2f(uu.y);
                } else if (dd == nodeB) {
                    ushort2 uu = xb2[(size_t)ovf[2 * e2 + 1] * (D / 2) + lane];
                    axB += bf2f(uu.x); ayB += bf2f(uu.y);
                }
            }
        }
        *(ushort2*)&sA[la * SROW + 2 * lane] = make_ushort2(f2bf(axA), f2bf(ayA));
        *(ushort2*)&sA[lb * SROW + 2 * lane] = make_ushort2(f2bf(axB), f2bf(ayB));
    }
    __syncthreads();

    // ---- phase 3: MFMA. wave wid -> tile (wid>>1), n0 groups (wid&1)*4.. ----
    int m = lane & 15, quad = lane >> 4;
    int tl = wid >> 1, ng0 = (wid & 1) * 4;
    const unsigned short* arow = &sA[(tl * 16 + m) * SROW + quad * 8];
    int xnode = node0 + tl * 16 + m;
    if (xnode >= N_NODES) xnode = 0;         // last block tail: clamp (store guarded)
    const unsigned short* xrow = xb + (size_t)xnode * D + quad * 8;

    floatx4 acc0 = (floatx4){0.f, 0.f, 0.f, 0.f};
    floatx4 acc1 = (floatx4){0.f, 0.f, 0.f, 0.f};
    floatx4 acc2 = (floatx4){0.f, 0.f, 0.f, 0.f};
    floatx4 acc3 = (floatx4){0.f, 0.f, 0.f, 0.f};
#pragma unroll
    for (int tt = 0; tt < 8; ++tt) {
        short8 afrag = (tt < 4) ? *(const short8*)(arow + tt * 32)
                                : *(const short8*)(xrow + (tt - 4) * 32);
        const unsigned short* bb = pwc + ((size_t)(tt * 8 + ng0) * 64 + lane) * 8;
        short8 b0 = *(const short8*)bb;
        short8 b1 = *(const short8*)(bb + 1 * 64 * 8);
        short8 b2 = *(const short8*)(bb + 2 * 64 * 8);
        short8 b3 = *(const short8*)(bb + 3 * 64 * 8);
        acc0 = __builtin_amdgcn_mfma_f32_16x16x32_bf16(afrag, b0, acc0, 0, 0, 0);
        acc1 = __builtin_amdgcn_mfma_f32_16x16x32_bf16(afrag, b1, acc1, 0, 0, 0);
        acc2 = __builtin_amdgcn_mfma_f32_16x16x32_bf16(afrag, b2, acc2, 0, 0, 0);
        acc3 = __builtin_amdgcn_mfma_f32_16x16x32_bf16(afrag, b3, acc3, 0, 0, 0);
    }

#pragma unroll
    for (int q = 0; q < 4; ++q) {
        floatx4 a = (q == 0) ? acc0 : (q == 1) ? acc1 : (q == 2) ? acc2 : acc3;
        int nn = (ng0 + q) * 16 + m;
        float bias = b_rel[nn];
#pragma unroll
        for (int r = 0; r < 4; ++r) {
            int node = node0 + tl * 16 + quad * 4 + r;
            if (node < N_NODES)
                out[(size_t)node * D + nn] = fmaxf(a[r] + bias, 0.f);
        }
    }
}

// ---------------- mid tier: fp32 CSR + VALU GEMM (unchanged machinery) ----------------
__global__ __launch_bounds__(256) void pack_w_kernel(const float* __restrict__ W,
                                                     float* __restrict__ pw) {
    int idx = blockIdx.x * 256 + threadIdx.x;
    if (idx >= D * D) return;
    int o = idx >> 7, k = idx & 127;
    pw[k * D + o] = W[o * D + k];
}

__global__ __launch_bounds__(256) void hist_kernel(const int* __restrict__ ei,
                                                   int* __restrict__ deg) {
    int i64 = wave_detect_i64(ei);
    int base = (blockIdx.x * 256 + threadIdx.x) * 4;
    if (base >= N_EDGES) return;
    int d0, d1, d2, d3;
    if (i64) {
        int4 a = *(const int4*)&ei[2 * N_EDGES + 2 * base];
        int4 b = *(const int4*)&ei[2 * N_EDGES + 2 * base + 4];
        d0 = a.x; d1 = a.z; d2 = b.x; d3 = b.z;
    } else {
        int4 v = *(const int4*)&ei[N_EDGES + base];
        d0 = v.x; d1 = v.y; d2 = v.z; d3 = v.w;
    }
    if ((unsigned)d0 < N_NODES) atomicAdd(&deg[d0], 1);
    if ((unsigned)d1 < N_NODES) atomicAdd(&deg[d1], 1);
    if ((unsigned)d2 < N_NODES) atomicAdd(&deg[d2], 1);
    if ((unsigned)d3 < N_NODES) atomicAdd(&deg[d3], 1);
}

__device__ __forceinline__ int wave_iscan(int v, int lane) {
#pragma unroll
    for (int off = 1; off < 64; off <<= 1) {
        int u = __shfl_up(v, off, 64);
        if (lane >= off) v += u;
    }
    return v;
}

__global__ __launch_bounds__(1024) void scan_kernel(const int* __restrict__ deg,
                                                    int* __restrict__ offsets,
                                                    int* __restrict__ cursor) {
    __shared__ int wsum[16];
    __shared__ int base_s;
    int t = threadIdx.x, lane = t & 63, w = t >> 6;
    if (t == 0) { base_s = 0; offsets[0] = 0; }
    __syncthreads();
    for (int c0 = 0; c0 < N_NODES; c0 += 1024) {
        int idx = c0 + t;
        int v = (idx < N_NODES) ? deg[idx] : 0;
        int inc = wave_iscan(v, lane);
        if (lane == 63) wsum[w] = inc;
        __syncthreads();
        if (w == 0) {
            int s = (lane < 16) ? wsum[lane] : 0;
            int si = wave_iscan(s, lane);
            if (lane < 16) wsum[lane] = si - s;
        }
        __syncthreads();
        int tot = base_s + wsum[w] + inc;
        if (idx < N_NODES) {
            offsets[idx + 1] = tot;
            cursor[idx] = tot - v;
        }
        __syncthreads();
        if (t == 1023) base_s = tot;
        __syncthreads();
    }
}

__global__ __launch_bounds__(256) void reorder_kernel(const int* __restrict__ ei,
                                                      int* __restrict__ cursor,
                                                      int* __restrict__ csr_src) {
    int i64 = wave_detect_i64(ei);
    int base = (blockIdx.x * 256 + threadIdx.x) * 4;
    if (base >= N_EDGES) return;
    int s0, s1, s2, s3, d0, d1, d2, d3;
    if (i64) {
        int4 a = *(const int4*)&ei[2 * base];
        int4 b = *(const int4*)&ei[2 * base + 4];
        s0 = a.x; s1 = a.z; s2 = b.x; s3 = b.z;
        int4 c = *(const int4*)&ei[2 * N_EDGES + 2 * base];
        int4 e = *(const int4*)&ei[2 * N_EDGES + 2 * base + 4];
        d0 = c.x; d1 = c.z; d2 = e.x; d3 = e.z;
    } else {
        int4 sv = *(const int4*)&ei[base];
        int4 dv = *(const int4*)&ei[N_EDGES + base];
        s0 = sv.x; s1 = sv.y; s2 = sv.z; s3 = sv.w;
        d0 = dv.x; d1 = dv.y; d2 = dv.z; d3 = dv.w;
    }
    bool v0 = (unsigned)s0 < N_NODES && (unsigned)d0 < N_NODES;
    bool v1 = (unsigned)s1 < N_NODES && (unsigned)d1 < N_NODES;
    bool v2 = (unsigned)s2 < N_NODES && (unsigned)d2 < N_NODES;
    bool v3 = (unsigned)s3 < N_NODES && (unsigned)d3 < N_NODES;
    int p0 = v0 ? atomicAdd(&cursor[d0], 1) : 0;
    int p1 = v1 ? atomicAdd(&cursor[d1], 1) : 0;
    int p2 = v2 ? atomicAdd(&cursor[d2], 1) : 0;
    int p3 = v3 ? atomicAdd(&cursor[d3], 1) : 0;
    if (v0) csr_src[p0] = s0;
    if (v1) csr_src[p1] = s1;
    if (v2) csr_src[p2] = s2;
    if (v3) csr_src[p3] = s3;
}

__global__ __launch_bounds__(256) void gather_kernel(const float2* __restrict__ x2,
                                                     const int* __restrict__ csr_src,
                                                     const int* __restrict__ offsets,
                                                     float2* __restrict__ agg2) {
    int node = blockIdx.x * 4 + (threadIdx.x >> 6);
    int lane = threadIdx.x & 63;
    if (node >= N_NODES) return;
    int beg = offsets[node], end = offsets[node + 1];
    float2 acc = make_float2(0.f, 0.f);
    for (int e = beg; e < end; ++e) {
        int s = csr_src[e];
        float2 f = x2[(size_t)s * (D / 2) + lane];
        acc.x += f.x;
        acc.y += f.y;
    }
    agg2[(size_t)node * (D / 2) + lane] = acc;
}

__global__ __launch_bounds__(256) void scatter_kernel(const float2* __restrict__ x2,
                                                      const int* __restrict__ ei,
                                                      const int* __restrict__ flag,
                                                      float* __restrict__ agg) {
    int wave = threadIdx.x >> 6;
    int lane = threadIdx.x & 63;
    int e = blockIdx.x * 4 + wave;
    if (e >= N_EDGES) return;
    int i64 = flag ? flag[0] : 0;
    int s, d;
    if (i64) { s = ei[2 * e]; d = ei[2 * N_EDGES + 2 * e]; }
    else     { s = ei[e];     d = ei[N_EDGES + e]; }
    if ((unsigned)s >= N_NODES || (unsigned)d >= N_NODES) return;
    float2 f = x2[(size_t)s * (D / 2) + lane];
    atomicAdd(&agg[(size_t)d * D + 2 * lane + 0], f.x);
    atomicAdd(&agg[(size_t)d * D + 2 * lane + 1], f.y);
}

__global__ __launch_bounds__(256) void gemm_f32_kernel(
        const float2* __restrict__ x2,
        const float* __restrict__ pwrel,
        const float* __restrict__ pwroot,
        const float* __restrict__ b_rel,
        float* __restrict__ out) {
    __shared__ float sWrel[KC * D];
    __shared__ float sWroot[KC * D];
    __shared__ float2 sAm[NPB * (KC / 2)];
    __shared__ float2 sXm[NPB * (KC / 2)];

    int t = threadIdx.x;
    int node0 = blockIdx.x * NPB;
    int tn = t >> 5;
    int to = t & 31;

    float acc[4][4];
#pragma unroll
    for (int a = 0; a < 4; ++a)
#pragma unroll
        for (int b = 0; b < 4; ++b) acc[a][b] = 0.0f;

    for (int c = 0; c < 4; ++c) {
        __syncthreads();
#pragma unroll
        for (int r = 0; r < 4; ++r) {
            int i = r * 256 + t;
            ((float4*)sWrel)[i]  = ((const float4*)(pwrel  + c * KC * D))[i];
            ((float4*)sWroot)[i] = ((const float4*)(pwroot + c * KC * D))[i];
        }
#pragma unroll
        for (int r = 0; r < 2; ++r) {
            int i = r * 256 + t;
            int n = i >> 4, k2 = i & 15;
            int node = node0 + n;
            float2 av = make_float2(0.f, 0.f), xv = make_float2(0.f, 0.f);
            if (node < N_NODES) {
                av = ((const float2*)out)[(size_t)node * (D / 2) + c * (KC / 2) + k2];
                xv = x2[(size_t)node * (D / 2) + c * (KC / 2) + k2];
            }
            sAm[i] = av;
            sXm[i] = xv;
        }
        __syncthreads();

#pragma unroll
        for (int k2 = 0; k2 < KC / 2; ++k2) {
            float4 wr0 = *(const float4*)&sWrel[(2 * k2 + 0) * D + to * 4];
            float4 wr1 = *(const float4*)&sWrel[(2 * k2 + 1) * D + to * 4];
            float4 wt0 = *(const float4*)&sWroot[(2 * k2 + 0) * D + to * 4];
            float4 wt1 = *(const float4*)&sWroot[(2 * k2 + 1) * D + to * 4];
#pragma unroll
            for (int ni = 0; ni < 4; ++ni) {
                float2 a  = sAm[(tn * 4 + ni) * (KC / 2) + k2];
                float2 xx = sXm[(tn * 4 + ni) * (KC / 2) + k2];
                acc[ni][0] += a.x * wr0.x + a.y * wr1.x + xx.x * wt0.x + xx.y * wt1.x;
                acc[ni][1] += a.x * wr0.y + a.y * wr1.y + xx.x * wt0.y + xx.y * wt1.y;
                acc[ni][2] += a.x * wr0.z + a.y * wr1.z + xx.x * wt0.z + xx.y * wt1.z;
                acc[ni][3] += a.x * wr0.w + a.y * wr1.w + xx.x * wt0.w + xx.y * wt1.w;
            }
        }
    }

    int o0 = to * 4;
    float4 bias = *(const float4*)&b_rel[o0];
#pragma unroll
    for (int ni = 0; ni < 4; ++ni) {
        int node = node0 + tn * 4 + ni;
        if (node >= N_NODES) continue;
        float4 v;
        v.x = fmaxf(acc[ni][0] + bias.x, 0.f);
        v.y = fmaxf(acc[ni][1] + bias.y, 0.f);
        v.z = fmaxf(acc[ni][2] + bias.z, 0.f);
        v.w = fmaxf(acc[ni][3] + bias.w, 0.f);
        *(float4*)&out[(size_t)node * D + o0] = v;
    }
}

__global__ __launch_bounds__(128) void gemm_fallback_kernel(const float* __restrict__ x,
                                                            const float* __restrict__ Wrel,
                                                            const float* __restrict__ Wroot,
                                                            const float* __restrict__ b_rel,
                                                            float* __restrict__ out) {
    __shared__ float rowA[D];
    __shared__ float rowX[D];
    int node = blockIdx.x;
    int o = threadIdx.x;
    rowA[o] = out[(size_t)node * D + o];
    rowX[o] = x[(size_t)node * D + o];
    __syncthreads();
    float acc = b_rel[o];
    const float4* wr = (const float4*)&Wrel[o * D];
    const float4* wt = (const float4*)&Wroot[o * D];
#pragma unroll 8
    for (int k4 = 0; k4 < D / 4; ++k4) {
        float4 w = wr[k4], u = wt[k4];
        const float* a = &rowA[k4 * 4];
        const float* xx = &rowX[k4 * 4];
        acc += a[0] * w.x + a[1] * w.y + a[2] * w.z + a[3] * w.w
             + xx[0] * u.x + xx[1] * u.y + xx[2] * u.z + xx[3] * u.w;
    }
    __syncthreads();
    out[(size_t)node * D + o] = fmaxf(acc, 0.f);
}

extern "C" void kernel_launch(void* const* d_in, const int* in_sizes, int n_in,
                              void* d_out, int out_size, void* d_ws, size_t ws_size,
                              hipStream_t stream) {
    const float* x      = (const float*)d_in[0];
    const int*   ei     = (const int*)d_in[1];
    const float* W_rel  = (const float*)d_in[2];
    const float* b_rel  = (const float*)d_in[3];
    const float* W_root = (const float*)d_in[4];
    float*       out    = (float*)d_out;

    // Full-tier ws layout (16 B aligned):
    //   flag(16) | pwc 64K | xb 12.8M | gcur 3136 | ovf_cnt 16 | bmem 4.8M |
    //   ovf 6.4M                                              total ~24.1 MiB
    char* p = (char*)d_ws;
    size_t o0 = 16;
    int*            flag    = (int*)p;
    unsigned short* pwc     = (unsigned short*)(p + o0);  o0 += (size_t)PACK_N * 2;
    unsigned short* xb      = (unsigned short*)(p + o0);  o0 += (size_t)N_NODES * D * 2;
    const size_t gcur_pad = ((size_t)NB * 4 + 15) & ~(size_t)15;
    int*            gcur    = (int*)(p + o0);             o0 += gcur_pad;
    int*            ovf_cnt = (int*)(p + o0);             o0 += 16;
    unsigned*       bmem    = (unsigned*)(p + o0);        o0 += (size_t)NB * BCAP * 4;
    int*            ovf     = (int*)(p + o0);             o0 += (size_t)N_EDGES * 8;
    const size_t need_full = o0;

    // Mid-tier layout: flag | pwrel 64K | pwroot 64K | deg | offs | csr
    size_t m0 = 16;
    float* m_pwrel  = (float*)(p + m0);  m0 += (size_t)D * D * 4;
    float* m_pwroot = (float*)(p + m0);  m0 += (size_t)D * D * 4;
    int*   m_deg    = (int*)(p + m0);    m0 += (size_t)N_NODES * 4;
    int*   m_offs   = (int*)(p + m0);    m0 += ((size_t)N_NODES + 1) * 4 + 12;
    m0 &= ~15ull;
    int*   m_csr    = (int*)(p + m0);    m0 += (size_t)N_EDGES * 4;
    const size_t need_mid = m0;
    const size_t need_pw  = 16 + 2 * (size_t)D * D * 4;

    const int eb4 = (N_EDGES / 4 + 255) / 256;   // 782 blocks for 4-edge kernels

    if (ws_size >= need_full) {
        hipMemsetAsync(gcur, 0, gcur_pad + 16, stream);   // gcur + ovf_cnt
        const int prep_total = CVT_N + PACK_N;
        const int grid1 = BINB + (prep_total + 255) / 256;
        stage1_kernel<<<grid1, 256, 0, stream>>>(
            (const float2*)x, (ushort2*)xb, W_rel, W_root, pwc, ei,
            gcur, bmem, ovf_cnt, ovf);
        GraphConvLayer_55783035240593_kernel<<<2 * NB, 256, 0, stream>>>(
            (const ushort2*)xb, xb, gcur, bmem, ovf_cnt, ovf, pwc, b_rel, out);
    } else if (ws_size >= need_mid) {
        pack_w_kernel<<<64, 256, 0, stream>>>(W_rel, m_pwrel);
        pack_w_kernel<<<64, 256, 0, stream>>>(W_root, m_pwroot);
        zero_f4_kernel<<<(N_NODES / 4 + 255) / 256, 256, 0, stream>>>((float4*)m_deg,
                                                                      N_NODES / 4);
        hist_kernel<<<eb4, 256, 0, stream>>>(ei, m_deg);
        scan_kernel<<<1, 1024, 0, stream>>>(m_deg, m_offs, m_deg);
        reorder_kernel<<<eb4, 256, 0, stream>>>(ei, m_deg, m_csr);
        gather_kernel<<<N_NODES / 4, 256, 0, stream>>>((const float2*)x, m_csr,
                                                       m_offs, (float2*)out);
        gemm_f32_kernel<<<(N_NODES + NPB - 1) / NPB, 256, 0, stream>>>(
            (const float2*)x, m_pwrel, m_pwroot, b_rel, out);
    } else {
        bool have_flag = ws_size >= 16;
        bool have_pw   = ws_size >= need_pw;
        if (have_flag) detect_kernel<<<1, 64, 0, stream>>>(ei, flag);
        if (have_pw) {
            pack_w_kernel<<<64, 256, 0, stream>>>(W_rel, m_pwrel);
            pack_w_kernel<<<64, 256, 0, stream>>>(W_root, m_pwroot);
        }
        int n4 = N_NODES * D / 4;
        zero_f4_kernel<<<(n4 + 255) / 256, 256, 0, stream>>>((float4*)out, n4);
        scatter_kernel<<<N_EDGES / 4, 256, 0, stream>>>((const float2*)x, ei,
                                                        have_flag ? flag : nullptr, out);
        if (have_pw)
            gemm_f32_kernel<<<(N_NODES + NPB - 1) / NPB, 256, 0, stream>>>(
                (const float2*)x, m_pwrel, m_pwroot, b_rel, out);
        else
            gemm_fallback_kernel<<<N_NODES, 128, 0, stream>>>(x, W_rel, W_root, b_rel, out);
    }
}

// Round 4
// 149.506 us; speedup vs baseline: 1.0142x; 1.0142x over previous
//
#include <hip/hip_runtime.h>
#include <hip/hip_bf16.h>

// GraphConv (PyG, aggr='add') + ReLU on MI355X — fp32 in/out, bf16 internals.
//   out = relu( segment_sum(x[src] -> dst) @ W_rel^T + b_rel + x @ W_root^T )
// N=50000, E=800000, D=128.
//
// Round 14 = Round 13 resubmitted verbatim (R13 bench was an infra failure:
// "container failed twice" — no kernel verdict). Design: bin into 3125
// buckets of 16 nodes (= one MFMA tile). Main kernel: 3125 blocks; each
// reads exactly its ~256 records (coalesced), builds the 16-node padded CSR
// in LDS in one pass, gathers node PAIRS (16 row loads in flight), then the
// proven R11 MFMA shape (2 accs/wave). LDS ~6 KB -> 8 blocks/CU.
// stage1: hist over 3125 buckets (12.5 KB LDS, base folded into cnt).

#define N_NODES 50000
#define N_EDGES 800000
#define D 128
#define SLOTS 48    // LDS slots per node (deg ~Poisson(16); tail -> rescan)
#define NB 3125     // buckets of 16 destination nodes (50000/16 exact)
#define BCAP 384    // records per bucket (expected 256, sigma 16; tail -> ovf)
#define BINB 196    // bin blocks: 196 * 4096 edges >= 800000
#define NPB 32      // nodes per fp32-gemm block (mid tier)
#define KC 32       // k per chunk (mid tier)
#define SROW 136    // LDS agg-row stride (ushorts); 272 B rows, 2-way banks = free

#define CVT_N  (N_NODES * (D / 2))   // 3,200,000 ushort2 conversions
#define PACK_N (8 * 8 * 64 * 8)      // 32,768 packed B-fragment elements

typedef __attribute__((ext_vector_type(8))) short short8;   // 8 bf16 = 4 VGPRs
typedef __attribute__((ext_vector_type(4))) float floatx4;

__device__ __forceinline__ float bf2f(unsigned short u) {
    return __uint_as_float((unsigned int)u << 16);
}
__device__ __forceinline__ unsigned short f2bf(float f) {
    __hip_bfloat16 h = __float2bfloat16(f);
    return *(unsigned short*)&h;
}

// int64 node-id array => every odd int32 word is 0 (ids < 50000).
// Must run with all 64 lanes active (call before any early return).
__device__ __forceinline__ int wave_detect_i64(const int* __restrict__ ei) {
    int lane = threadIdx.x & 63;
    int v = ei[2 * lane + 1];
    return __ballot(v == 0) == ~0ull;
}

// ---------------- utility ----------------
__global__ __launch_bounds__(256) void zero_f4_kernel(float4* __restrict__ p, int n4) {
    int i = blockIdx.x * 256 + threadIdx.x;
    if (i < n4) p[i] = make_float4(0.f, 0.f, 0.f, 0.f);
}

// flag-based detect kept only for the low-tier scatter fallback
__global__ void detect_kernel(const int* __restrict__ ei, int* __restrict__ flag) {
    if (threadIdx.x == 0 && blockIdx.x == 0) {
        int any = 0;
        for (int i = 0; i < 64; ++i) any |= ei[2 * i + 1];
        flag[0] = (any == 0) ? 1 : 0;
    }
}

// ---------------- stage1: edge binning + cvt_x + pack_frag ----------------
// Blocks [0, BINB): bin 4096 edges each into NB buckets of 16 dst nodes.
// Blocks [BINB, ...): prep work (x -> bf16, W packing).
// gcur (NB ints) and ovf_cnt must be zeroed before launch (hipMemsetAsync).
__global__ __launch_bounds__(256) void stage1_kernel(const float2* __restrict__ x2,
                                                     ushort2* __restrict__ xb2,
                                                     const float* __restrict__ Wrel,
                                                     const float* __restrict__ Wroot,
                                                     unsigned short* __restrict__ pwc,
                                                     const int* __restrict__ ei,
                                                     int* __restrict__ gcur,
                                                     unsigned* __restrict__ bmem,
                                                     int* __restrict__ ovf_cnt,
                                                     int* __restrict__ ovf) {
    __shared__ int lds_cnt[NB];          // 12.5 KB: counts, then bases in-place
    if (blockIdx.x < BINB) {
        int t = threadIdx.x;
        int i64 = wave_detect_i64(ei);
        for (int i = t; i < NB; i += 256) lds_cnt[i] = 0;
        __syncthreads();

        unsigned rec[16];
        int rnk[16];
#pragma unroll
        for (int g = 0; g < 4; ++g) {
            int base = blockIdx.x * 4096 + g * 1024 + t * 4;
            int s0 = -1, s1 = -1, s2 = -1, s3 = -1;
            int d0 = -1, d1 = -1, d2 = -1, d3 = -1;
            if (base < N_EDGES) {            // N_EDGES % 4 == 0: all-or-nothing
                if (i64) {
                    int4 a = *(const int4*)&ei[2 * base];
                    int4 b = *(const int4*)&ei[2 * base + 4];
                    s0 = a.x; s1 = a.z; s2 = b.x; s3 = b.z;
                    int4 c = *(const int4*)&ei[2 * N_EDGES + 2 * base];
                    int4 e = *(const int4*)&ei[2 * N_EDGES + 2 * base + 4];
                    d0 = c.x; d1 = c.z; d2 = e.x; d3 = e.z;
                } else {
                    int4 sv = *(const int4*)&ei[base];
                    int4 dv = *(const int4*)&ei[N_EDGES + base];
                    s0 = sv.x; s1 = sv.y; s2 = sv.z; s3 = sv.w;
                    d0 = dv.x; d1 = dv.y; d2 = dv.z; d3 = dv.w;
                }
            }
#define BINP(idx, ss, dd)                                                        \
            {                                                                    \
                bool ok = (unsigned)(ss) < N_NODES && (unsigned)(dd) < N_NODES;  \
                rec[idx] = ok ? (((unsigned)(dd) << 16) | (unsigned)(ss))        \
                              : 0xFFFFFFFFu;                                     \
                rnk[idx] = ok ? atomicAdd(&lds_cnt[(unsigned)(dd) >> 4], 1) : 0; \
            }
            BINP(g * 4 + 0, s0, d0)
            BINP(g * 4 + 1, s1, d1)
            BINP(g * 4 + 2, s2, d2)
            BINP(g * 4 + 3, s3, d3)
#undef BINP
        }
        __syncthreads();
        for (int i = t; i < NB; i += 256) {
            int c = lds_cnt[i];
            int b = c ? atomicAdd(&gcur[i], c) : 0;
            lds_cnt[i] = b;                  // now holds this block's base
        }
        __syncthreads();
#pragma unroll
        for (int idx = 0; idx < 16; ++idx) {
            unsigned r = rec[idx];
            if (r != 0xFFFFFFFFu) {
                int bk = (int)(r >> 20);             // dst >> 4
                int pos = lds_cnt[bk] + rnk[idx];
                if (pos < BCAP) {
                    bmem[(size_t)bk * BCAP + pos] = r;
                } else {                             // bucket overflow: rare
                    int o = atomicAdd(ovf_cnt, 1);
                    ovf[2 * o] = (int)(r >> 16);
                    ovf[2 * o + 1] = (int)(r & 0xFFFFu);
                }
            }
        }
    } else {
        int i = (blockIdx.x - BINB) * 256 + threadIdx.x;
        if (i < CVT_N) {
            float2 f = x2[i];
            xb2[i] = make_ushort2(f2bf(f.x), f2bf(f.y));
        } else if (i < CVT_N + PACK_N) {
            // pwc[((t*8+n0)*64+lane)*8+j] = W_cat[n0*16+(lane&15)][t*32+(lane>>4)*8+j]
            int idx  = i - CVT_N;
            int j    = idx & 7;
            int lane = (idx >> 3) & 63;
            int n0   = (idx >> 9) & 7;
            int t    = idx >> 12;
            int n = n0 * 16 + (lane & 15);
            int k = t * 32 + (lane >> 4) * 8 + j;
            float w = (k < D) ? Wrel[n * D + k] : Wroot[n * D + (k - D)];
            pwc[idx] = f2bf(w);
        }
    }
}

// ---------------- fused CSR-build + gather + MFMA GEMM + bias + ReLU ----------------
// Block = one bucket = one 16-node MFMA tile (grid NB = 3125, 4 waves).
// Phase 1: read this bucket's ~256 records (coalesced), build padded CSR in
// LDS (1 pass, LDS atomics only). Phase 2: wave wid gathers nodes
// 4wid..4wid+3 as 2 PAIRS (16 independent row loads in flight; slot indices
// from LDS -> no global dependency chain). Phase 3: R11 MFMA shape: wave wid
// computes n0 groups {2wid, 2wid+1}.
// Degree overflow (kk > SLOTS): ignore slots, rescan bucket records (exact).
// Bucket overflow (> BCAP): handled via global ovf list (tov scan).
// Layouts (verified): A[m=lane&15][k=quad*8+j], D: col=lane&15, row=quad*4+reg.
__global__ __launch_bounds__(256) void GraphConvLayer_55783035240593_kernel(
        const ushort2* __restrict__ xb2,
        const unsigned short* __restrict__ xb,
        const int* __restrict__ gcur,
        const unsigned* __restrict__ bmem,
        const int* __restrict__ ovf_cnt,
        const int* __restrict__ ovf,
        const unsigned short* __restrict__ pwc,
        const float* __restrict__ b_rel,
        float* __restrict__ out) {
    __shared__ unsigned short sA[16 * SROW];        // 4352 B
    __shared__ unsigned short slotsL[16 * SLOTS];   // 1536 B
    __shared__ int lc[16];
    int t = threadIdx.x;
    int wid = t >> 6, lane = t & 63;
    int bkt = blockIdx.x;
    int node0 = bkt * 16;                   // 50000 = 3125 * 16, exact

    int n = gcur[bkt];                      // issue early (hides latency)
    int tov = ovf_cnt[0];                   // broadcast, L2-hot
    if (t < 16) lc[t] = 0;
    __syncthreads();

    // ---- phase 1: build padded CSR in LDS from this bucket's records ----
    if (n > BCAP) n = BCAP;                 // entries past BCAP went to ovf
    for (int e = t; e < n; e += 256) {
        unsigned r = bmem[(size_t)bkt * BCAP + e];
        int dl = (int)((r >> 16) & 15);
        int p = atomicAdd(&lc[dl], 1);
        if (p < SLOTS) slotsL[dl * SLOTS + p] = (unsigned short)(r & 0xFFFFu);
    }
    __syncthreads();

    // ---- phase 2: gather, 4 nodes per wave, processed in pairs ----
    for (int pp = 0; pp < 2; ++pp) {
        int la = wid * 4 + pp * 2, lb = la + 1;
        int nodeA = node0 + la, nodeB = node0 + lb;
        int kkA = lc[la], kkB = lc[lb];
        int kA = (kkA > SLOTS) ? 0 : kkA;    // overflowed nodes: rescan path
        int kB = (kkB > SLOTS) ? 0 : kkB;
        int myA = (lane < kA) ? (int)slotsL[la * SLOTS + lane] : 0;
        int myB = (lane < kB) ? (int)slotsL[lb * SLOTS + lane] : 0;
        float axA = 0.f, ayA = 0.f, axB = 0.f, ayB = 0.f;
        int jmax = kA > kB ? kA : kB;
        for (int j = 0; j < jmax; j += 8) {
            bool doA = j < kA, doB = j < kB;
            ushort2 u[8], v[8];
            if (doA) {
                int s[8];
#pragma unroll
                for (int i = 0; i < 8; ++i) s[i] = __shfl(myA, j + i);
#pragma unroll
                for (int i = 0; i < 8; ++i) u[i] = xb2[(size_t)s[i] * (D / 2) + lane];
            }
            if (doB) {
                int s[8];
#pragma unroll
                for (int i = 0; i < 8; ++i) s[i] = __shfl(myB, j + i);
#pragma unroll
                for (int i = 0; i < 8; ++i) v[i] = xb2[(size_t)s[i] * (D / 2) + lane];
            }
            if (doA) {
#pragma unroll
                for (int i = 0; i < 8; ++i) {
                    float mm = (j + i < kA) ? 1.f : 0.f;
                    axA += mm * bf2f(u[i].x);
                    ayA += mm * bf2f(u[i].y);
                }
            }
            if (doB) {
#pragma unroll
                for (int i = 0; i < 8; ++i) {
                    float mm = (j + i < kB) ? 1.f : 0.f;
                    axB += mm * bf2f(v[i].x);
                    ayB += mm * bf2f(v[i].y);
                }
            }
        }
        if (kkA > SLOTS) {                   // rare: exact rescan of records
            for (int e = 0; e < n; ++e) {
                unsigned r = bmem[(size_t)bkt * BCAP + e];
                if ((int)(r >> 16) == nodeA) {
                    ushort2 uu = xb2[(size_t)(r & 0xFFFFu) * (D / 2) + lane];
                    axA += bf2f(uu.x); ayA += bf2f(uu.y);
                }
            }
        }
        if (kkB > SLOTS) {
            for (int e = 0; e < n; ++e) {
                unsigned r = bmem[(size_t)bkt * BCAP + e];
                if ((int)(r >> 16) == nodeB) {
                    ushort2 uu = xb2[(size_t)(r & 0xFFFFu) * (D / 2) + lane];
                    axB += bf2f(uu.x); ayB += bf2f(uu.y);
                }
            }
        }
        if (tov > 0) {                       // bucket-overflow entries: rare
            for (int e2 = 0; e2 < tov; ++e2) {
                int dd = ovf[2 * e2];
                if (dd == nodeA) {
                    ushort2 uu = xb2[(size_t)ovf[2 * e2 + 1] * (D / 2) + lane];
                    axA += bf2f(uu.x); ayA += bf2f(uu.y);
                } else if (dd == nodeB) {
                    ushort2 uu = xb2[(size_t)ovf[2 * e2 + 1] * (D / 2) + lane];
                    axB += bf2f(uu.x); ayB += bf2f(uu.y);
                }
            }
        }
        *(ushort2*)&sA[la * SROW + 2 * lane] = make_ushort2(f2bf(axA), f2bf(ayA));
        *(ushort2*)&sA[lb * SROW + 2 * lane] = make_ushort2(f2bf(axB), f2bf(ayB));
    }
    __syncthreads();

    // ---- phase 3: MFMA. wave wid computes n0 = 2*wid, 2*wid+1 ----
    int m = lane & 15, quad = lane >> 4;
    const unsigned short* arow = &sA[m * SROW + quad * 8];
    const unsigned short* xrow = xb + (size_t)(node0 + m) * D + quad * 8;

    floatx4 acc0 = (floatx4){0.f, 0.f, 0.f, 0.f};
    floatx4 acc1 = (floatx4){0.f, 0.f, 0.f, 0.f};
#pragma unroll
    for (int tt = 0; tt < 8; ++tt) {
        short8 afrag = (tt < 4) ? *(const short8*)(arow + tt * 32)
                                : *(const short8*)(xrow + (tt - 4) * 32);
        const unsigned short* bb = pwc + ((size_t)(tt * 8 + wid * 2) * 64 + lane) * 8;
        short8 b0 = *(const short8*)bb;
        short8 b1 = *(const short8*)(bb + 64 * 8);
        acc0 = __builtin_amdgcn_mfma_f32_16x16x32_bf16(afrag, b0, acc0, 0, 0, 0);
        acc1 = __builtin_amdgcn_mfma_f32_16x16x32_bf16(afrag, b1, acc1, 0, 0, 0);
    }

#pragma unroll
    for (int q = 0; q < 2; ++q) {
        floatx4 a = q ? acc1 : acc0;
        int nn = (wid * 2 + q) * 16 + m;
        float bias = b_rel[nn];
#pragma unroll
        for (int r = 0; r < 4; ++r) {
            int node = node0 + quad * 4 + r;
            out[(size_t)node * D + nn] = fmaxf(a[r] + bias, 0.f);
        }
    }
}

// ---------------- mid tier: fp32 CSR + VALU GEMM (unchanged machinery) ----------------
__global__ __launch_bounds__(256) void pack_w_kernel(const float* __restrict__ W,
                                                     float* __restrict__ pw) {
    int idx = blockIdx.x * 256 + threadIdx.x;
    if (idx >= D * D) return;
    int o = idx >> 7, k = idx & 127;
    pw[k * D + o] = W[o * D + k];
}

__global__ __launch_bounds__(256) void hist_kernel(const int* __restrict__ ei,
                                                   int* __restrict__ deg) {
    int i64 = wave_detect_i64(ei);
    int base = (blockIdx.x * 256 + threadIdx.x) * 4;
    if (base >= N_EDGES) return;
    int d0, d1, d2, d3;
    if (i64) {
        int4 a = *(const int4*)&ei[2 * N_EDGES + 2 * base];
        int4 b = *(const int4*)&ei[2 * N_EDGES + 2 * base + 4];
        d0 = a.x; d1 = a.z; d2 = b.x; d3 = b.z;
    } else {
        int4 v = *(const int4*)&ei[N_EDGES + base];
        d0 = v.x; d1 = v.y; d2 = v.z; d3 = v.w;
    }
    if ((unsigned)d0 < N_NODES) atomicAdd(&deg[d0], 1);
    if ((unsigned)d1 < N_NODES) atomicAdd(&deg[d1], 1);
    if ((unsigned)d2 < N_NODES) atomicAdd(&deg[d2], 1);
    if ((unsigned)d3 < N_NODES) atomicAdd(&deg[d3], 1);
}

__device__ __forceinline__ int wave_iscan(int v, int lane) {
#pragma unroll
    for (int off = 1; off < 64; off <<= 1) {
        int u = __shfl_up(v, off, 64);
        if (lane >= off) v += u;
    }
    return v;
}

__global__ __launch_bounds__(1024) void scan_kernel(const int* __restrict__ deg,
                                                    int* __restrict__ offsets,
                                                    int* __restrict__ cursor) {
    __shared__ int wsum[16];
    __shared__ int base_s;
    int t = threadIdx.x, lane = t & 63, w = t >> 6;
    if (t == 0) { base_s = 0; offsets[0] = 0; }
    __syncthreads();
    for (int c0 = 0; c0 < N_NODES; c0 += 1024) {
        int idx = c0 + t;
        int v = (idx < N_NODES) ? deg[idx] : 0;
        int inc = wave_iscan(v, lane);
        if (lane == 63) wsum[w] = inc;
        __syncthreads();
        if (w == 0) {
            int s = (lane < 16) ? wsum[lane] : 0;
            int si = wave_iscan(s, lane);
            if (lane < 16) wsum[lane] = si - s;
        }
        __syncthreads();
        int tot = base_s + wsum[w] + inc;
        if (idx < N_NODES) {
            offsets[idx + 1] = tot;
            cursor[idx] = tot - v;
        }
        __syncthreads();
        if (t == 1023) base_s = tot;
        __syncthreads();
    }
}

__global__ __launch_bounds__(256) void reorder_kernel(const int* __restrict__ ei,
                                                      int* __restrict__ cursor,
                                                      int* __restrict__ csr_src) {
    int i64 = wave_detect_i64(ei);
    int base = (blockIdx.x * 256 + threadIdx.x) * 4;
    if (base >= N_EDGES) return;
    int s0, s1, s2, s3, d0, d1, d2, d3;
    if (i64) {
        int4 a = *(const int4*)&ei[2 * base];
        int4 b = *(const int4*)&ei[2 * base + 4];
        s0 = a.x; s1 = a.z; s2 = b.x; s3 = b.z;
        int4 c = *(const int4*)&ei[2 * N_EDGES + 2 * base];
        int4 e = *(const int4*)&ei[2 * N_EDGES + 2 * base + 4];
        d0 = c.x; d1 = c.z; d2 = e.x; d3 = e.z;
    } else {
        int4 sv = *(const int4*)&ei[base];
        int4 dv = *(const int4*)&ei[N_EDGES + base];
        s0 = sv.x; s1 = sv.y; s2 = sv.z; s3 = sv.w;
        d0 = dv.x; d1 = dv.y; d2 = dv.z; d3 = dv.w;
    }
    bool v0 = (unsigned)s0 < N_NODES && (unsigned)d0 < N_NODES;
    bool v1 = (unsigned)s1 < N_NODES && (unsigned)d1 < N_NODES;
    bool v2 = (unsigned)s2 < N_NODES && (unsigned)d2 < N_NODES;
    bool v3 = (unsigned)s3 < N_NODES && (unsigned)d3 < N_NODES;
    int p0 = v0 ? atomicAdd(&cursor[d0], 1) : 0;
    int p1 = v1 ? atomicAdd(&cursor[d1], 1) : 0;
    int p2 = v2 ? atomicAdd(&cursor[d2], 1) : 0;
    int p3 = v3 ? atomicAdd(&cursor[d3], 1) : 0;
    if (v0) csr_src[p0] = s0;
    if (v1) csr_src[p1] = s1;
    if (v2) csr_src[p2] = s2;
    if (v3) csr_src[p3] = s3;
}

__global__ __launch_bounds__(256) void gather_kernel(const float2* __restrict__ x2,
                                                     const int* __restrict__ csr_src,
                                                     const int* __restrict__ offsets,
                                                     float2* __restrict__ agg2) {
    int node = blockIdx.x * 4 + (threadIdx.x >> 6);
    int lane = threadIdx.x & 63;
    if (node >= N_NODES) return;
    int beg = offsets[node], end = offsets[node + 1];
    float2 acc = make_float2(0.f, 0.f);
    for (int e = beg; e < end; ++e) {
        int s = csr_src[e];
        float2 f = x2[(size_t)s * (D / 2) + lane];
        acc.x += f.x;
        acc.y += f.y;
    }
    agg2[(size_t)node * (D / 2) + lane] = acc;
}

__global__ __launch_bounds__(256) void scatter_kernel(const float2* __restrict__ x2,
                                                      const int* __restrict__ ei,
                                                      const int* __restrict__ flag,
                                                      float* __restrict__ agg) {
    int wave = threadIdx.x >> 6;
    int lane = threadIdx.x & 63;
    int e = blockIdx.x * 4 + wave;
    if (e >= N_EDGES) return;
    int i64 = flag ? flag[0] : 0;
    int s, d;
    if (i64) { s = ei[2 * e]; d = ei[2 * N_EDGES + 2 * e]; }
    else     { s = ei[e];     d = ei[N_EDGES + e]; }
    if ((unsigned)s >= N_NODES || (unsigned)d >= N_NODES) return;
    float2 f = x2[(size_t)s * (D / 2) + lane];
    atomicAdd(&agg[(size_t)d * D + 2 * lane + 0], f.x);
    atomicAdd(&agg[(size_t)d * D + 2 * lane + 1], f.y);
}

__global__ __launch_bounds__(256) void gemm_f32_kernel(
        const float2* __restrict__ x2,
        const float* __restrict__ pwrel,
        const float* __restrict__ pwroot,
        const float* __restrict__ b_rel,
        float* __restrict__ out) {
    __shared__ float sWrel[KC * D];
    __shared__ float sWroot[KC * D];
    __shared__ float2 sAm[NPB * (KC / 2)];
    __shared__ float2 sXm[NPB * (KC / 2)];

    int t = threadIdx.x;
    int node0 = blockIdx.x * NPB;
    int tn = t >> 5;
    int to = t & 31;

    float acc[4][4];
#pragma unroll
    for (int a = 0; a < 4; ++a)
#pragma unroll
        for (int b = 0; b < 4; ++b) acc[a][b] = 0.0f;

    for (int c = 0; c < 4; ++c) {
        __syncthreads();
#pragma unroll
        for (int r = 0; r < 4; ++r) {
            int i = r * 256 + t;
            ((float4*)sWrel)[i]  = ((const float4*)(pwrel  + c * KC * D))[i];
            ((float4*)sWroot)[i] = ((const float4*)(pwroot + c * KC * D))[i];
        }
#pragma unroll
        for (int r = 0; r < 2; ++r) {
            int i = r * 256 + t;
            int n = i >> 4, k2 = i & 15;
            int node = node0 + n;
            float2 av = make_float2(0.f, 0.f), xv = make_float2(0.f, 0.f);
            if (node < N_NODES) {
                av = ((const float2*)out)[(size_t)node * (D / 2) + c * (KC / 2) + k2];
                xv = x2[(size_t)node * (D / 2) + c * (KC / 2) + k2];
            }
            sAm[i] = av;
            sXm[i] = xv;
        }
        __syncthreads();

#pragma unroll
        for (int k2 = 0; k2 < KC / 2; ++k2) {
            float4 wr0 = *(const float4*)&sWrel[(2 * k2 + 0) * D + to * 4];
            float4 wr1 = *(const float4*)&sWrel[(2 * k2 + 1) * D + to * 4];
            float4 wt0 = *(const float4*)&sWroot[(2 * k2 + 0) * D + to * 4];
            float4 wt1 = *(const float4*)&sWroot[(2 * k2 + 1) * D + to * 4];
#pragma unroll
            for (int ni = 0; ni < 4; ++ni) {
                float2 a  = sAm[(tn * 4 + ni) * (KC / 2) + k2];
                float2 xx = sXm[(tn * 4 + ni) * (KC / 2) + k2];
                acc[ni][0] += a.x * wr0.x + a.y * wr1.x + xx.x * wt0.x + xx.y * wt1.x;
                acc[ni][1] += a.x * wr0.y + a.y * wr1.y + xx.x * wt0.y + xx.y * wt1.y;
                acc[ni][2] += a.x * wr0.z + a.y * wr1.z + xx.x * wt0.z + xx.y * wt1.z;
                acc[ni][3] += a.x * wr0.w + a.y * wr1.w + xx.x * wt0.w + xx.y * wt1.w;
            }
        }
    }

    int o0 = to * 4;
    float4 bias = *(const float4*)&b_rel[o0];
#pragma unroll
    for (int ni = 0; ni < 4; ++ni) {
        int node = node0 + tn * 4 + ni;
        if (node >= N_NODES) continue;
        float4 v;
        v.x = fmaxf(acc[ni][0] + bias.x, 0.f);
        v.y = fmaxf(acc[ni][1] + bias.y, 0.f);
        v.z = fmaxf(acc[ni][2] + bias.z, 0.f);
        v.w = fmaxf(acc[ni][3] + bias.w, 0.f);
        *(float4*)&out[(size_t)node * D + o0] = v;
    }
}

__global__ __launch_bounds__(128) void gemm_fallback_kernel(const float* __restrict__ x,
                                                            const float* __restrict__ Wrel,
                                                            const float* __restrict__ Wroot,
                                                            const float* __restrict__ b_rel,
                                                            float* __restrict__ out) {
    __shared__ float rowA[D];
    __shared__ float rowX[D];
    int node = blockIdx.x;
    int o = threadIdx.x;
    rowA[o] = out[(size_t)node * D + o];
    rowX[o] = x[(size_t)node * D + o];
    __syncthreads();
    float acc = b_rel[o];
    const float4* wr = (const float4*)&Wrel[o * D];
    const float4* wt = (const float4*)&Wroot[o * D];
#pragma unroll 8
    for (int k4 = 0; k4 < D / 4; ++k4) {
        float4 w = wr[k4], u = wt[k4];
        const float* a = &rowA[k4 * 4];
        const float* xx = &rowX[k4 * 4];
        acc += a[0] * w.x + a[1] * w.y + a[2] * w.z + a[3] * w.w
             + xx[0] * u.x + xx[1] * u.y + xx[2] * u.z + xx[3] * u.w;
    }
    __syncthreads();
    out[(size_t)node * D + o] = fmaxf(acc, 0.f);
}

extern "C" void kernel_launch(void* const* d_in, const int* in_sizes, int n_in,
                              void* d_out, int out_size, void* d_ws, size_t ws_size,
                              hipStream_t stream) {
    const float* x      = (const float*)d_in[0];
    const int*   ei     = (const int*)d_in[1];
    const float* W_rel  = (const float*)d_in[2];
    const float* b_rel  = (const float*)d_in[3];
    const float* W_root = (const float*)d_in[4];
    float*       out    = (float*)d_out;

    // Full-tier ws layout (16 B aligned):
    //   flag(16) | pwc 64K | xb 12.8M | gcur 12.5K | ovf_cnt 16 | bmem 4.8M |
    //   ovf 6.4M                                              total ~24.1 MiB
    char* p = (char*)d_ws;
    size_t o0 = 16;
    int*            flag    = (int*)p;
    unsigned short* pwc     = (unsigned short*)(p + o0);  o0 += (size_t)PACK_N * 2;
    unsigned short* xb      = (unsigned short*)(p + o0);  o0 += (size_t)N_NODES * D * 2;
    const size_t gcur_pad = ((size_t)NB * 4 + 15) & ~(size_t)15;
    int*            gcur    = (int*)(p + o0);             o0 += gcur_pad;
    int*            ovf_cnt = (int*)(p + o0);             o0 += 16;
    unsigned*       bmem    = (unsigned*)(p + o0);        o0 += (size_t)NB * BCAP * 4;
    int*            ovf     = (int*)(p + o0);             o0 += (size_t)N_EDGES * 8;
    const size_t need_full = o0;

    // Mid-tier layout: flag | pwrel 64K | pwroot 64K | deg | offs | csr
    size_t m0 = 16;
    float* m_pwrel  = (float*)(p + m0);  m0 += (size_t)D * D * 4;
    float* m_pwroot = (float*)(p + m0);  m0 += (size_t)D * D * 4;
    int*   m_deg    = (int*)(p + m0);    m0 += (size_t)N_NODES * 4;
    int*   m_offs   = (int*)(p + m0);    m0 += ((size_t)N_NODES + 1) * 4 + 12;
    m0 &= ~15ull;
    int*   m_csr    = (int*)(p + m0);    m0 += (size_t)N_EDGES * 4;
    const size_t need_mid = m0;
    const size_t need_pw  = 16 + 2 * (size_t)D * D * 4;

    const int eb4 = (N_EDGES / 4 + 255) / 256;   // 782 blocks for 4-edge kernels

    if (ws_size >= need_full) {
        hipMemsetAsync(gcur, 0, gcur_pad + 16, stream);   // gcur + ovf_cnt
        const int prep_total = CVT_N + PACK_N;
        const int grid1 = BINB + (prep_total + 255) / 256;
        stage1_kernel<<<grid1, 256, 0, stream>>>(
            (const float2*)x, (ushort2*)xb, W_rel, W_root, pwc, ei,
            gcur, bmem, ovf_cnt, ovf);
        GraphConvLayer_55783035240593_kernel<<<NB, 256, 0, stream>>>(
            (const ushort2*)xb, xb, gcur, bmem, ovf_cnt, ovf, pwc, b_rel, out);
    } else if (ws_size >= need_mid) {
        pack_w_kernel<<<64, 256, 0, stream>>>(W_rel, m_pwrel);
        pack_w_kernel<<<64, 256, 0, stream>>>(W_root, m_pwroot);
        zero_f4_kernel<<<(N_NODES / 4 + 255) / 256, 256, 0, stream>>>((float4*)m_deg,
                                                                      N_NODES / 4);
        hist_kernel<<<eb4, 256, 0, stream>>>(ei, m_deg);
        scan_kernel<<<1, 1024, 0, stream>>>(m_deg, m_offs, m_deg);
        reorder_kernel<<<eb4, 256, 0, stream>>>(ei, m_deg, m_csr);
        gather_kernel<<<N_NODES / 4, 256, 0, stream>>>((const float2*)x, m_csr,
                                                       m_offs, (float2*)out);
        gemm_f32_kernel<<<(N_NODES + NPB - 1) / NPB, 256, 0, stream>>>(
            (const float2*)x, m_pwrel, m_pwroot, b_rel, out);
    } else {
        bool have_flag = ws_size >= 16;
        bool have_pw   = ws_size >= need_pw;
        if (have_flag) detect_kernel<<<1, 64, 0, stream>>>(ei, flag);
        if (have_pw) {
            pack_w_kernel<<<64, 256, 0, stream>>>(W_rel, m_pwrel);
            pack_w_kernel<<<64, 256, 0, stream>>>(W_root, m_pwroot);
        }
        int n4 = N_NODES * D / 4;
        zero_f4_kernel<<<(n4 + 255) / 256, 256, 0, stream>>>((float4*)out, n4);
        scatter_kernel<<<N_EDGES / 4, 256, 0, stream>>>((const float2*)x, ei,
                                                        have_flag ? flag : nullptr, out);
        if (have_pw)
            gemm_f32_kernel<<<(N_NODES + NPB - 1) / NPB, 256, 0, stream>>>(
                (const float2*)x, m_pwrel, m_pwroot, b_rel, out);
        else
            gemm_fallback_kernel<<<N_NODES, 128, 0, stream>>>(x, W_rel, W_root, b_rel, out);
    }
}

// Round 6
// 147.844 us; speedup vs baseline: 1.0256x; 1.0112x over previous
//
#include <hip/hip_runtime.h>
#include <hip/hip_bf16.h>

// GraphConv (PyG, aggr='add') + ReLU on MI355X — fp32 in/out, bf16 internals.
//   out = relu( segment_sum(x[src] -> dst) @ W_rel^T + b_rel + x @ W_root^T )
// N=50000, E=800000, D=128.
//
// Round 16 = Round 15 with two correctness fixes (R15 failed absmax=57):
//   BUG 1: slot prefill was `if (t < 384)` in a 256-thread block -> slots
//          512..767 (nodes 10-15 per tile) never got the dummy fill; the
//          branch-free gather summed garbage rows. Fix: strided loop.
//   BUG 2 (latent): degree-overflow nodes left real srcs in slots while the
//          rescan re-added all records (double count). Fix: force my=dummy
//          when kk > SLOTS.
// Design unchanged: NB=782 binning (measured cheaper), main blocks read
// their quarter of the bucket, 4 nodes/wave gathered together (32 loads in
// flight), dummy-row branch-free inner loop, R11 MFMA shape.

#define N_NODES 50000
#define N_EDGES 800000
#define D 128
#define SLOTS 48    // LDS slots per node (deg ~Poisson(16); tail -> rescan)
#define NB 782      // bin buckets of 64 destination nodes (ceil(50000/64))
#define TILES 3125  // main blocks: 16-node MFMA tiles (50000/16 exact)
#define BCAP 1536   // records per bucket (expected 1024; tail -> ovf)
#define BINB 196    // bin blocks: 196 * 4096 edges >= 800000
#define NPB 32      // nodes per fp32-gemm block (mid tier)
#define KC 32       // k per chunk (mid tier)
#define SROW 136    // LDS agg-row stride (ushorts); 272 B rows, 2-way banks = free
#define DUMMY 50000 // zero row appended to xb

#define CVT_N  (N_NODES * (D / 2))   // 3,200,000 ushort2 conversions
#define PACK_N (8 * 8 * 64 * 8)      // 32,768 packed B-fragment elements
#define ZROW_N (D / 2)               // 64 ushort2: zero dummy row 50000

typedef __attribute__((ext_vector_type(8))) short short8;   // 8 bf16 = 4 VGPRs
typedef __attribute__((ext_vector_type(4))) float floatx4;

__device__ __forceinline__ float bf2f(unsigned short u) {
    return __uint_as_float((unsigned int)u << 16);
}
__device__ __forceinline__ unsigned short f2bf(float f) {
    __hip_bfloat16 h = __float2bfloat16(f);
    return *(unsigned short*)&h;
}

// int64 node-id array => every odd int32 word is 0 (ids < 50000).
// Must run with all 64 lanes active (call before any early return).
__device__ __forceinline__ int wave_detect_i64(const int* __restrict__ ei) {
    int lane = threadIdx.x & 63;
    int v = ei[2 * lane + 1];
    return __ballot(v == 0) == ~0ull;
}

// ---------------- utility ----------------
__global__ __launch_bounds__(256) void zero_f4_kernel(float4* __restrict__ p, int n4) {
    int i = blockIdx.x * 256 + threadIdx.x;
    if (i < n4) p[i] = make_float4(0.f, 0.f, 0.f, 0.f);
}

// flag-based detect kept only for the low-tier scatter fallback
__global__ void detect_kernel(const int* __restrict__ ei, int* __restrict__ flag) {
    if (threadIdx.x == 0 && blockIdx.x == 0) {
        int any = 0;
        for (int i = 0; i < 64; ++i) any |= ei[2 * i + 1];
        flag[0] = (any == 0) ? 1 : 0;
    }
}

// ---------------- stage1: edge binning + cvt_x + pack_frag ----------------
// Blocks [0, BINB): bin 4096 edges each into NB buckets of 64 dst nodes.
// Blocks [BINB, ...): prep work (x -> bf16, W packing, zero dummy row).
// gcur (NB ints) and ovf_cnt must be zeroed before launch (hipMemsetAsync).
__global__ __launch_bounds__(256) void stage1_kernel(const float2* __restrict__ x2,
                                                     ushort2* __restrict__ xb2,
                                                     const float* __restrict__ Wrel,
                                                     const float* __restrict__ Wroot,
                                                     unsigned short* __restrict__ pwc,
                                                     const int* __restrict__ ei,
                                                     int* __restrict__ gcur,
                                                     unsigned* __restrict__ bmem,
                                                     int* __restrict__ ovf_cnt,
                                                     int* __restrict__ ovf) {
    __shared__ int lds_cnt[NB];
    __shared__ int lds_base[NB];
    if (blockIdx.x < BINB) {
        int t = threadIdx.x;
        int i64 = wave_detect_i64(ei);
        for (int i = t; i < NB; i += 256) lds_cnt[i] = 0;
        __syncthreads();

        unsigned rec[16];
        int rnk[16];
#pragma unroll
        for (int g = 0; g < 4; ++g) {
            int base = blockIdx.x * 4096 + g * 1024 + t * 4;
            int s0 = -1, s1 = -1, s2 = -1, s3 = -1;
            int d0 = -1, d1 = -1, d2 = -1, d3 = -1;
            if (base < N_EDGES) {            // N_EDGES % 4 == 0: all-or-nothing
                if (i64) {
                    int4 a = *(const int4*)&ei[2 * base];
                    int4 b = *(const int4*)&ei[2 * base + 4];
                    s0 = a.x; s1 = a.z; s2 = b.x; s3 = b.z;
                    int4 c = *(const int4*)&ei[2 * N_EDGES + 2 * base];
                    int4 e = *(const int4*)&ei[2 * N_EDGES + 2 * base + 4];
                    d0 = c.x; d1 = c.z; d2 = e.x; d3 = e.z;
                } else {
                    int4 sv = *(const int4*)&ei[base];
                    int4 dv = *(const int4*)&ei[N_EDGES + base];
                    s0 = sv.x; s1 = sv.y; s2 = sv.z; s3 = sv.w;
                    d0 = dv.x; d1 = dv.y; d2 = dv.z; d3 = dv.w;
                }
            }
#define BINP(idx, ss, dd)                                                        \
            {                                                                    \
                bool ok = (unsigned)(ss) < N_NODES && (unsigned)(dd) < N_NODES;  \
                rec[idx] = ok ? (((unsigned)(dd) << 16) | (unsigned)(ss))        \
                              : 0xFFFFFFFFu;                                     \
                rnk[idx] = ok ? atomicAdd(&lds_cnt[(unsigned)(dd) >> 6], 1) : 0; \
            }
            BINP(g * 4 + 0, s0, d0)
            BINP(g * 4 + 1, s1, d1)
            BINP(g * 4 + 2, s2, d2)
            BINP(g * 4 + 3, s3, d3)
#undef BINP
        }
        __syncthreads();
        for (int i = t; i < NB; i += 256) {
            int c = lds_cnt[i];
            lds_base[i] = c ? atomicAdd(&gcur[i], c) : 0;
        }
        __syncthreads();
#pragma unroll
        for (int idx = 0; idx < 16; ++idx) {
            unsigned r = rec[idx];
            if (r != 0xFFFFFFFFu) {
                int bk = (int)(r >> 22);             // dst >> 6
                int pos = lds_base[bk] + rnk[idx];
                if (pos < BCAP) {
                    bmem[(size_t)bk * BCAP + pos] = r;
                } else {                             // bucket overflow: rare
                    int o = atomicAdd(ovf_cnt, 1);
                    ovf[2 * o] = (int)(r >> 16);
                    ovf[2 * o + 1] = (int)(r & 0xFFFFu);
                }
            }
        }
    } else {
        int i = (blockIdx.x - BINB) * 256 + threadIdx.x;
        if (i < CVT_N) {
            float2 f = x2[i];
            xb2[i] = make_ushort2(f2bf(f.x), f2bf(f.y));
        } else if (i < CVT_N + PACK_N) {
            // pwc[((t*8+n0)*64+lane)*8+j] = W_cat[n0*16+(lane&15)][t*32+(lane>>4)*8+j]
            int idx  = i - CVT_N;
            int j    = idx & 7;
            int lane = (idx >> 3) & 63;
            int n0   = (idx >> 9) & 7;
            int t    = idx >> 12;
            int n = n0 * 16 + (lane & 15);
            int k = t * 32 + (lane >> 4) * 8 + j;
            float w = (k < D) ? Wrel[n * D + k] : Wroot[n * D + (k - D)];
            pwc[idx] = f2bf(w);
        } else if (i < CVT_N + PACK_N + ZROW_N) {
            xb2[CVT_N + (i - CVT_N - PACK_N)] = make_ushort2(0, 0);  // dummy row
        }
    }
}

// ---------------- fused CSR-build + gather + MFMA GEMM + bias + ReLU ----------------
// Block = one 16-node tile (grid TILES = 3125, 4 waves). Its records live in
// quarter q = tile&3 of bucket tile>>2. Phase 1: scan bucket records
// (coalesced, 4 blocks share the region -> L2-hot), keep own quarter, build
// padded CSR in LDS; empty slots point at dummy row 50000 (all zeros).
// Phase 2: wave wid gathers its 4 nodes TOGETHER: 32 row loads in flight,
// branch-free, mask-free (dummies add 0). Phase 3: R11 MFMA shape.
// Degree overflow (kk > SLOTS): my forced to DUMMY, rescan records (exact).
// Bucket overflow (> BCAP): handled via global ovf list (tov scan).
// Layouts (verified): A[m=lane&15][k=quad*8+j], D: col=lane&15, row=quad*4+reg.
__global__ __launch_bounds__(256, 8) void GraphConvLayer_55783035240593_kernel(
        const ushort2* __restrict__ xb2,
        const unsigned short* __restrict__ xb,
        const int* __restrict__ gcur,
        const unsigned* __restrict__ bmem,
        const int* __restrict__ ovf_cnt,
        const int* __restrict__ ovf,
        const unsigned short* __restrict__ pwc,
        const float* __restrict__ b_rel,
        float* __restrict__ out) {
    __shared__ unsigned short sA[16 * SROW];        // 4352 B
    __shared__ unsigned short slotsL[16 * SLOTS];   // 1536 B
    __shared__ int lc[16];
    int t = threadIdx.x;
    int wid = t >> 6, lane = t & 63;
    int tile = blockIdx.x;
    int bkt = tile >> 2;
    unsigned q = (unsigned)(tile & 3);
    int node0 = tile * 16;                  // 50000 = 3125 * 16, exact

    int n = gcur[bkt];                      // issue early (hides latency)
    int tov = ovf_cnt[0];                   // broadcast, L2-hot
    if (t < 16) lc[t] = 0;
    for (int i = t; i < 16 * SLOTS / 2; i += 256)   // FIX: strided (384 > 256)
        ((unsigned*)slotsL)[i] = (DUMMY << 16) | DUMMY;
    __syncthreads();

    // ---- phase 1: build padded CSR in LDS from own quarter of the bucket ----
    if (n > BCAP) n = BCAP;                 // entries past BCAP went to ovf
    for (int e = t; e < n; e += 256) {
        unsigned r = bmem[(size_t)bkt * BCAP + e];
        if (((r >> 20) & 3u) != q) continue;
        int dl = (int)((r >> 16) & 15);
        int p = atomicAdd(&lc[dl], 1);
        if (p < SLOTS) slotsL[dl * SLOTS + p] = (unsigned short)(r & 0xFFFFu);
    }
    __syncthreads();

    // ---- phase 2: gather, 4 nodes per wave, all simultaneously ----
    int kk0 = lc[wid * 4 + 0], kk1 = lc[wid * 4 + 1];
    int kk2 = lc[wid * 4 + 2], kk3 = lc[wid * 4 + 3];
    int kc0 = (kk0 > SLOTS) ? 0 : kk0;      // overflowed nodes: rescan path
    int kc1 = (kk1 > SLOTS) ? 0 : kk1;
    int kc2 = (kk2 > SLOTS) ? 0 : kk2;
    int kc3 = (kk3 > SLOTS) ? 0 : kk3;
    int sl = lane < SLOTS ? lane : 0;
    // FIX: overflowed node -> force dummy so the branch-free loop adds 0
    int my0 = (kk0 > SLOTS) ? DUMMY : (int)slotsL[(wid * 4 + 0) * SLOTS + sl];
    int my1 = (kk1 > SLOTS) ? DUMMY : (int)slotsL[(wid * 4 + 1) * SLOTS + sl];
    int my2 = (kk2 > SLOTS) ? DUMMY : (int)slotsL[(wid * 4 + 2) * SLOTS + sl];
    int my3 = (kk3 > SLOTS) ? DUMMY : (int)slotsL[(wid * 4 + 3) * SLOTS + sl];
    int jmax = kc0 > kc1 ? kc0 : kc1;
    jmax = kc2 > jmax ? kc2 : jmax;
    jmax = kc3 > jmax ? kc3 : jmax;
    float ax0 = 0.f, ay0 = 0.f, ax1 = 0.f, ay1 = 0.f;
    float ax2 = 0.f, ay2 = 0.f, ax3 = 0.f, ay3 = 0.f;
    for (int j = 0; j < jmax; j += 8) {
        ushort2 u0[8], u1[8], u2[8], u3[8];
#pragma unroll
        for (int v = 0; v < 8; ++v) {
            int s = __shfl(my0, j + v);     // dummy 50000 beyond kc (zero row)
            u0[v] = xb2[(size_t)s * (D / 2) + lane];
        }
#pragma unroll
        for (int v = 0; v < 8; ++v) {
            int s = __shfl(my1, j + v);
            u1[v] = xb2[(size_t)s * (D / 2) + lane];
        }
#pragma unroll
        for (int v = 0; v < 8; ++v) {
            int s = __shfl(my2, j + v);
            u2[v] = xb2[(size_t)s * (D / 2) + lane];
        }
#pragma unroll
        for (int v = 0; v < 8; ++v) {
            int s = __shfl(my3, j + v);
            u3[v] = xb2[(size_t)s * (D / 2) + lane];
        }
#pragma unroll
        for (int v = 0; v < 8; ++v) { ax0 += bf2f(u0[v].x); ay0 += bf2f(u0[v].y); }
#pragma unroll
        for (int v = 0; v < 8; ++v) { ax1 += bf2f(u1[v].x); ay1 += bf2f(u1[v].y); }
#pragma unroll
        for (int v = 0; v < 8; ++v) { ax2 += bf2f(u2[v].x); ay2 += bf2f(u2[v].y); }
#pragma unroll
        for (int v = 0; v < 8; ++v) { ax3 += bf2f(u3[v].x); ay3 += bf2f(u3[v].y); }
    }

    // ---- rare paths: degree overflow (rescan) and bucket overflow ----
    int nodeb = node0 + wid * 4;
    if (kk0 > SLOTS || kk1 > SLOTS || kk2 > SLOTS || kk3 > SLOTS) {
        for (int e = 0; e < n; ++e) {
            unsigned r = bmem[(size_t)bkt * BCAP + e];
            int dd = (int)(r >> 16);
            ushort2 uu;
            if (kk0 > SLOTS && dd == nodeb + 0) {
                uu = xb2[(size_t)(r & 0xFFFFu) * (D / 2) + lane];
                ax0 += bf2f(uu.x); ay0 += bf2f(uu.y);
            } else if (kk1 > SLOTS && dd == nodeb + 1) {
                uu = xb2[(size_t)(r & 0xFFFFu) * (D / 2) + lane];
                ax1 += bf2f(uu.x); ay1 += bf2f(uu.y);
            } else if (kk2 > SLOTS && dd == nodeb + 2) {
                uu = xb2[(size_t)(r & 0xFFFFu) * (D / 2) + lane];
                ax2 += bf2f(uu.x); ay2 += bf2f(uu.y);
            } else if (kk3 > SLOTS && dd == nodeb + 3) {
                uu = xb2[(size_t)(r & 0xFFFFu) * (D / 2) + lane];
                ax3 += bf2f(uu.x); ay3 += bf2f(uu.y);
            }
        }
    }
    if (tov > 0) {                          // bucket-overflow entries: rare
        for (int e2 = 0; e2 < tov; ++e2) {
            int dd = ovf[2 * e2];
            int rel = dd - nodeb;
            if ((unsigned)rel < 4u) {
                ushort2 uu = xb2[(size_t)ovf[2 * e2 + 1] * (D / 2) + lane];
                if (rel == 0)      { ax0 += bf2f(uu.x); ay0 += bf2f(uu.y); }
                else if (rel == 1) { ax1 += bf2f(uu.x); ay1 += bf2f(uu.y); }
                else if (rel == 2) { ax2 += bf2f(uu.x); ay2 += bf2f(uu.y); }
                else               { ax3 += bf2f(uu.x); ay3 += bf2f(uu.y); }
            }
        }
    }
    *(ushort2*)&sA[(wid * 4 + 0) * SROW + 2 * lane] = make_ushort2(f2bf(ax0), f2bf(ay0));
    *(ushort2*)&sA[(wid * 4 + 1) * SROW + 2 * lane] = make_ushort2(f2bf(ax1), f2bf(ay1));
    *(ushort2*)&sA[(wid * 4 + 2) * SROW + 2 * lane] = make_ushort2(f2bf(ax2), f2bf(ay2));
    *(ushort2*)&sA[(wid * 4 + 3) * SROW + 2 * lane] = make_ushort2(f2bf(ax3), f2bf(ay3));
    __syncthreads();

    // ---- phase 3: MFMA. wave wid computes n0 = 2*wid, 2*wid+1 ----
    int m = lane & 15, quad = lane >> 4;
    const unsigned short* arow = &sA[m * SROW + quad * 8];
    const unsigned short* xrow = xb + (size_t)(node0 + m) * D + quad * 8;

    floatx4 acc0 = (floatx4){0.f, 0.f, 0.f, 0.f};
    floatx4 acc1 = (floatx4){0.f, 0.f, 0.f, 0.f};
#pragma unroll
    for (int tt = 0; tt < 8; ++tt) {
        short8 afrag = (tt < 4) ? *(const short8*)(arow + tt * 32)
                                : *(const short8*)(xrow + (tt - 4) * 32);
        const unsigned short* bb = pwc + ((size_t)(tt * 8 + wid * 2) * 64 + lane) * 8;
        short8 b0 = *(const short8*)bb;
        short8 b1 = *(const short8*)(bb + 64 * 8);
        acc0 = __builtin_amdgcn_mfma_f32_16x16x32_bf16(afrag, b0, acc0, 0, 0, 0);
        acc1 = __builtin_amdgcn_mfma_f32_16x16x32_bf16(afrag, b1, acc1, 0, 0, 0);
    }

#pragma unroll
    for (int qq = 0; qq < 2; ++qq) {
        floatx4 a = qq ? acc1 : acc0;
        int nn = (wid * 2 + qq) * 16 + m;
        float bias = b_rel[nn];
#pragma unroll
        for (int r = 0; r < 4; ++r) {
            int node = node0 + quad * 4 + r;
            out[(size_t)node * D + nn] = fmaxf(a[r] + bias, 0.f);
        }
    }
}

// ---------------- mid tier: fp32 CSR + VALU GEMM (unchanged machinery) ----------------
__global__ __launch_bounds__(256) void pack_w_kernel(const float* __restrict__ W,
                                                     float* __restrict__ pw) {
    int idx = blockIdx.x * 256 + threadIdx.x;
    if (idx >= D * D) return;
    int o = idx >> 7, k = idx & 127;
    pw[k * D + o] = W[o * D + k];
}

__global__ __launch_bounds__(256) void hist_kernel(const int* __restrict__ ei,
                                                   int* __restrict__ deg) {
    int i64 = wave_detect_i64(ei);
    int base = (blockIdx.x * 256 + threadIdx.x) * 4;
    if (base >= N_EDGES) return;
    int d0, d1, d2, d3;
    if (i64) {
        int4 a = *(const int4*)&ei[2 * N_EDGES + 2 * base];
        int4 b = *(const int4*)&ei[2 * N_EDGES + 2 * base + 4];
        d0 = a.x; d1 = a.z; d2 = b.x; d3 = b.z;
    } else {
        int4 v = *(const int4*)&ei[N_EDGES + base];
        d0 = v.x; d1 = v.y; d2 = v.z; d3 = v.w;
    }
    if ((unsigned)d0 < N_NODES) atomicAdd(&deg[d0], 1);
    if ((unsigned)d1 < N_NODES) atomicAdd(&deg[d1], 1);
    if ((unsigned)d2 < N_NODES) atomicAdd(&deg[d2], 1);
    if ((unsigned)d3 < N_NODES) atomicAdd(&deg[d3], 1);
}

__device__ __forceinline__ int wave_iscan(int v, int lane) {
#pragma unroll
    for (int off = 1; off < 64; off <<= 1) {
        int u = __shfl_up(v, off, 64);
        if (lane >= off) v += u;
    }
    return v;
}

__global__ __launch_bounds__(1024) void scan_kernel(const int* __restrict__ deg,
                                                    int* __restrict__ offsets,
                                                    int* __restrict__ cursor) {
    __shared__ int wsum[16];
    __shared__ int base_s;
    int t = threadIdx.x, lane = t & 63, w = t >> 6;
    if (t == 0) { base_s = 0; offsets[0] = 0; }
    __syncthreads();
    for (int c0 = 0; c0 < N_NODES; c0 += 1024) {
        int idx = c0 + t;
        int v = (idx < N_NODES) ? deg[idx] : 0;
        int inc = wave_iscan(v, lane);
        if (lane == 63) wsum[w] = inc;
        __syncthreads();
        if (w == 0) {
            int s = (lane < 16) ? wsum[lane] : 0;
            int si = wave_iscan(s, lane);
            if (lane < 16) wsum[lane] = si - s;
        }
        __syncthreads();
        int tot = base_s + wsum[w] + inc;
        if (idx < N_NODES) {
            offsets[idx + 1] = tot;
            cursor[idx] = tot - v;
        }
        __syncthreads();
        if (t == 1023) base_s = tot;
        __syncthreads();
    }
}

__global__ __launch_bounds__(256) void reorder_kernel(const int* __restrict__ ei,
                                                      int* __restrict__ cursor,
                                                      int* __restrict__ csr_src) {
    int i64 = wave_detect_i64(ei);
    int base = (blockIdx.x * 256 + threadIdx.x) * 4;
    if (base >= N_EDGES) return;
    int s0, s1, s2, s3, d0, d1, d2, d3;
    if (i64) {
        int4 a = *(const int4*)&ei[2 * base];
        int4 b = *(const int4*)&ei[2 * base + 4];
        s0 = a.x; s1 = a.z; s2 = b.x; s3 = b.z;
        int4 c = *(const int4*)&ei[2 * N_EDGES + 2 * base];
        int4 e = *(const int4*)&ei[2 * N_EDGES + 2 * base + 4];
        d0 = c.x; d1 = c.z; d2 = e.x; d3 = e.z;
    } else {
        int4 sv = *(const int4*)&ei[base];
        int4 dv = *(const int4*)&ei[N_EDGES + base];
        s0 = sv.x; s1 = sv.y; s2 = sv.z; s3 = sv.w;
        d0 = dv.x; d1 = dv.y; d2 = dv.z; d3 = dv.w;
    }
    bool v0 = (unsigned)s0 < N_NODES && (unsigned)d0 < N_NODES;
    bool v1 = (unsigned)s1 < N_NODES && (unsigned)d1 < N_NODES;
    bool v2 = (unsigned)s2 < N_NODES && (unsigned)d2 < N_NODES;
    bool v3 = (unsigned)s3 < N_NODES && (unsigned)d3 < N_NODES;
    int p0 = v0 ? atomicAdd(&cursor[d0], 1) : 0;
    int p1 = v1 ? atomicAdd(&cursor[d1], 1) : 0;
    int p2 = v2 ? atomicAdd(&cursor[d2], 1) : 0;
    int p3 = v3 ? atomicAdd(&cursor[d3], 1) : 0;
    if (v0) csr_src[p0] = s0;
    if (v1) csr_src[p1] = s1;
    if (v2) csr_src[p2] = s2;
    if (v3) csr_src[p3] = s3;
}

__global__ __launch_bounds__(256) void gather_kernel(const float2* __restrict__ x2,
                                                     const int* __restrict__ csr_src,
                                                     const int* __restrict__ offsets,
                                                     float2* __restrict__ agg2) {
    int node = blockIdx.x * 4 + (threadIdx.x >> 6);
    int lane = threadIdx.x & 63;
    if (node >= N_NODES) return;
    int beg = offsets[node], end = offsets[node + 1];
    float2 acc = make_float2(0.f, 0.f);
    for (int e = beg; e < end; ++e) {
        int s = csr_src[e];
        float2 f = x2[(size_t)s * (D / 2) + lane];
        acc.x += f.x;
        acc.y += f.y;
    }
    agg2[(size_t)node * (D / 2) + lane] = acc;
}

__global__ __launch_bounds__(256) void scatter_kernel(const float2* __restrict__ x2,
                                                      const int* __restrict__ ei,
                                                      const int* __restrict__ flag,
                                                      float* __restrict__ agg) {
    int wave = threadIdx.x >> 6;
    int lane = threadIdx.x & 63;
    int e = blockIdx.x * 4 + wave;
    if (e >= N_EDGES) return;
    int i64 = flag ? flag[0] : 0;
    int s, d;
    if (i64) { s = ei[2 * e]; d = ei[2 * N_EDGES + 2 * e]; }
    else     { s = ei[e];     d = ei[N_EDGES + e]; }
    if ((unsigned)s >= N_NODES || (unsigned)d >= N_NODES) return;
    float2 f = x2[(size_t)s * (D / 2) + lane];
    atomicAdd(&agg[(size_t)d * D + 2 * lane + 0], f.x);
    atomicAdd(&agg[(size_t)d * D + 2 * lane + 1], f.y);
}

__global__ __launch_bounds__(256) void gemm_f32_kernel(
        const float2* __restrict__ x2,
        const float* __restrict__ pwrel,
        const float* __restrict__ pwroot,
        const float* __restrict__ b_rel,
        float* __restrict__ out) {
    __shared__ float sWrel[KC * D];
    __shared__ float sWroot[KC * D];
    __shared__ float2 sAm[NPB * (KC / 2)];
    __shared__ float2 sXm[NPB * (KC / 2)];

    int t = threadIdx.x;
    int node0 = blockIdx.x * NPB;
    int tn = t >> 5;
    int to = t & 31;

    float acc[4][4];
#pragma unroll
    for (int a = 0; a < 4; ++a)
#pragma unroll
        for (int b = 0; b < 4; ++b) acc[a][b] = 0.0f;

    for (int c = 0; c < 4; ++c) {
        __syncthreads();
#pragma unroll
        for (int r = 0; r < 4; ++r) {
            int i = r * 256 + t;
            ((float4*)sWrel)[i]  = ((const float4*)(pwrel  + c * KC * D))[i];
            ((float4*)sWroot)[i] = ((const float4*)(pwroot + c * KC * D))[i];
        }
#pragma unroll
        for (int r = 0; r < 2; ++r) {
            int i = r * 256 + t;
            int n = i >> 4, k2 = i & 15;
            int node = node0 + n;
            float2 av = make_float2(0.f, 0.f), xv = make_float2(0.f, 0.f);
            if (node < N_NODES) {
                av = ((const float2*)out)[(size_t)node * (D / 2) + c * (KC / 2) + k2];
                xv = x2[(size_t)node * (D / 2) + c * (KC / 2) + k2];
            }
            sAm[i] = av;
            sXm[i] = xv;
        }
        __syncthreads();

#pragma unroll
        for (int k2 = 0; k2 < KC / 2; ++k2) {
            float4 wr0 = *(const float4*)&sWrel[(2 * k2 + 0) * D + to * 4];
            float4 wr1 = *(const float4*)&sWrel[(2 * k2 + 1) * D + to * 4];
            float4 wt0 = *(const float4*)&sWroot[(2 * k2 + 0) * D + to * 4];
            float4 wt1 = *(const float4*)&sWroot[(2 * k2 + 1) * D + to * 4];
#pragma unroll
            for (int ni = 0; ni < 4; ++ni) {
                float2 a  = sAm[(tn * 4 + ni) * (KC / 2) + k2];
                float2 xx = sXm[(tn * 4 + ni) * (KC / 2) + k2];
                acc[ni][0] += a.x * wr0.x + a.y * wr1.x + xx.x * wt0.x + xx.y * wt1.x;
                acc[ni][1] += a.x * wr0.y + a.y * wr1.y + xx.x * wt0.y + xx.y * wt1.y;
                acc[ni][2] += a.x * wr0.z + a.y * wr1.z + xx.x * wt0.z + xx.y * wt1.z;
                acc[ni][3] += a.x * wr0.w + a.y * wr1.w + xx.x * wt0.w + xx.y * wt1.w;
            }
        }
    }

    int o0 = to * 4;
    float4 bias = *(const float4*)&b_rel[o0];
#pragma unroll
    for (int ni = 0; ni < 4; ++ni) {
        int node = node0 + tn * 4 + ni;
        if (node >= N_NODES) continue;
        float4 v;
        v.x = fmaxf(acc[ni][0] + bias.x, 0.f);
        v.y = fmaxf(acc[ni][1] + bias.y, 0.f);
        v.z = fmaxf(acc[ni][2] + bias.z, 0.f);
        v.w = fmaxf(acc[ni][3] + bias.w, 0.f);
        *(float4*)&out[(size_t)node * D + o0] = v;
    }
}

__global__ __launch_bounds__(128) void gemm_fallback_kernel(const float* __restrict__ x,
                                                            const float* __restrict__ Wrel,
                                                            const float* __restrict__ Wroot,
                                                            const float* __restrict__ b_rel,
                                                            float* __restrict__ out) {
    __shared__ float rowA[D];
    __shared__ float rowX[D];
    int node = blockIdx.x;
    int o = threadIdx.x;
    rowA[o] = out[(size_t)node * D + o];
    rowX[o] = x[(size_t)node * D + o];
    __syncthreads();
    float acc = b_rel[o];
    const float4* wr = (const float4*)&Wrel[o * D];
    const float4* wt = (const float4*)&Wroot[o * D];
#pragma unroll 8
    for (int k4 = 0; k4 < D / 4; ++k4) {
        float4 w = wr[k4], u = wt[k4];
        const float* a = &rowA[k4 * 4];
        const float* xx = &rowX[k4 * 4];
        acc += a[0] * w.x + a[1] * w.y + a[2] * w.z + a[3] * w.w
             + xx[0] * u.x + xx[1] * u.y + xx[2] * u.z + xx[3] * u.w;
    }
    __syncthreads();
    out[(size_t)node * D + o] = fmaxf(acc, 0.f);
}

extern "C" void kernel_launch(void* const* d_in, const int* in_sizes, int n_in,
                              void* d_out, int out_size, void* d_ws, size_t ws_size,
                              hipStream_t stream) {
    const float* x      = (const float*)d_in[0];
    const int*   ei     = (const int*)d_in[1];
    const float* W_rel  = (const float*)d_in[2];
    const float* b_rel  = (const float*)d_in[3];
    const float* W_root = (const float*)d_in[4];
    float*       out    = (float*)d_out;

    // Full-tier ws layout (16 B aligned):
    //   flag(16) | pwc 64K | xb 12.8M(+dummy row) | gcur 3136 | ovf_cnt 16 |
    //   bmem 4.8M | ovf 6.4M                                  total ~24.1 MiB
    char* p = (char*)d_ws;
    size_t o0 = 16;
    int*            flag    = (int*)p;
    unsigned short* pwc     = (unsigned short*)(p + o0);  o0 += (size_t)PACK_N * 2;
    unsigned short* xb      = (unsigned short*)(p + o0);  o0 += (size_t)(N_NODES + 1) * D * 2;
    const size_t gcur_pad = ((size_t)NB * 4 + 15) & ~(size_t)15;
    int*            gcur    = (int*)(p + o0);             o0 += gcur_pad;
    int*            ovf_cnt = (int*)(p + o0);             o0 += 16;
    unsigned*       bmem    = (unsigned*)(p + o0);        o0 += (size_t)NB * BCAP * 4;
    int*            ovf     = (int*)(p + o0);             o0 += (size_t)N_EDGES * 8;
    const size_t need_full = o0;

    // Mid-tier layout: flag | pwrel 64K | pwroot 64K | deg | offs | csr
    size_t m0 = 16;
    float* m_pwrel  = (float*)(p + m0);  m0 += (size_t)D * D * 4;
    float* m_pwroot = (float*)(p + m0);  m0 += (size_t)D * D * 4;
    int*   m_deg    = (int*)(p + m0);    m0 += (size_t)N_NODES * 4;
    int*   m_offs   = (int*)(p + m0);    m0 += ((size_t)N_NODES + 1) * 4 + 12;
    m0 &= ~15ull;
    int*   m_csr    = (int*)(p + m0);    m0 += (size_t)N_EDGES * 4;
    const size_t need_mid = m0;
    const size_t need_pw  = 16 + 2 * (size_t)D * D * 4;

    const int eb4 = (N_EDGES / 4 + 255) / 256;   // 782 blocks for 4-edge kernels

    if (ws_size >= need_full) {
        hipMemsetAsync(gcur, 0, gcur_pad + 16, stream);   // gcur + ovf_cnt
        const int prep_total = CVT_N + PACK_N + ZROW_N;
        const int grid1 = BINB + (prep_total + 255) / 256;
        stage1_kernel<<<grid1, 256, 0, stream>>>(
            (const float2*)x, (ushort2*)xb, W_rel, W_root, pwc, ei,
            gcur, bmem, ovf_cnt, ovf);
        GraphConvLayer_55783035240593_kernel<<<TILES, 256, 0, stream>>>(
            (const ushort2*)xb, xb, gcur, bmem, ovf_cnt, ovf, pwc, b_rel, out);
    } else if (ws_size >= need_mid) {
        pack_w_kernel<<<64, 256, 0, stream>>>(W_rel, m_pwrel);
        pack_w_kernel<<<64, 256, 0, stream>>>(W_root, m_pwroot);
        zero_f4_kernel<<<(N_NODES / 4 + 255) / 256, 256, 0, stream>>>((float4*)m_deg,
                                                                      N_NODES / 4);
        hist_kernel<<<eb4, 256, 0, stream>>>(ei, m_deg);
        scan_kernel<<<1, 1024, 0, stream>>>(m_deg, m_offs, m_deg);
        reorder_kernel<<<eb4, 256, 0, stream>>>(ei, m_deg, m_csr);
        gather_kernel<<<N_NODES / 4, 256, 0, stream>>>((const float2*)x, m_csr,
                                                       m_offs, (float2*)out);
        gemm_f32_kernel<<<(N_NODES + NPB - 1) / NPB, 256, 0, stream>>>(
            (const float2*)x, m_pwrel, m_pwroot, b_rel, out);
    } else {
        bool have_flag = ws_size >= 16;
        bool have_pw   = ws_size >= need_pw;
        if (have_flag) detect_kernel<<<1, 64, 0, stream>>>(ei, flag);
        if (have_pw) {
            pack_w_kernel<<<64, 256, 0, stream>>>(W_rel, m_pwrel);
            pack_w_kernel<<<64, 256, 0, stream>>>(W_root, m_pwroot);
        }
        int n4 = N_NODES * D / 4;
        zero_f4_kernel<<<(n4 + 255) / 256, 256, 0, stream>>>((float4*)out, n4);
        scatter_kernel<<<N_EDGES / 4, 256, 0, stream>>>((const float2*)x, ei,
                                                        have_flag ? flag : nullptr, out);
        if (have_pw)
            gemm_f32_kernel<<<(N_NODES + NPB - 1) / NPB, 256, 0, stream>>>(
                (const float2*)x, m_pwrel, m_pwroot, b_rel, out);
        else
            gemm_fallback_kernel<<<N_NODES, 128, 0, stream>>>(x, W_rel, W_root, b_rel, out);
    }
}